// Round 2
// baseline (622.697 us; speedup 1.0000x reference)
//
#include <hip/hip_runtime.h>
#include <hip/hip_bf16.h>
#include <math.h>

#define BB 16
#define SS 2048
#define DD 128
#define BQ 64      // q rows per block (4 waves x 16)
#define BK 64      // keys per tile
#define PLD 72     // P LDS row stride (bf16), 144B rows, 16B-aligned
#define VLD 72
#define NELEM (BB * SS * DD)   // 4194304 per tensor

typedef __attribute__((ext_vector_type(8))) __bf16 bf16x8;
typedef __attribute__((ext_vector_type(4))) __bf16 bf16x4;
typedef __attribute__((ext_vector_type(4))) float f32x4;

// ---------- prep 1: q*scale and k -> bf16 row-major ----------
__global__ __launch_bounds__(256)
void prep_qk(const float* __restrict__ q, const float* __restrict__ k,
             __bf16* __restrict__ qs, __bf16* __restrict__ kb) {
  const int NCH = NELEM / 8;
  int g = blockIdx.x * 256 + threadIdx.x;  // 0 .. 2*NCH-1
  const float* src;
  __bf16* dst;
  float sc;
  if (g < NCH) { src = q; dst = qs; sc = 0.08838834764831845f; }
  else         { g -= NCH; src = k; dst = kb; sc = 1.0f; }
  const float4* p = (const float4*)(src + (size_t)g * 8);
  float4 a = p[0], b = p[1];
  bf16x8 w;
  w[0] = (__bf16)(a.x * sc); w[1] = (__bf16)(a.y * sc);
  w[2] = (__bf16)(a.z * sc); w[3] = (__bf16)(a.w * sc);
  w[4] = (__bf16)(b.x * sc); w[5] = (__bf16)(b.y * sc);
  w[6] = (__bf16)(b.z * sc); w[7] = (__bf16)(b.w * sc);
  ((bf16x8*)dst)[g] = w;
}

// ---------- prep 2: v -> bf16 transposed [b][d][s] ----------
__global__ __launch_bounds__(256)
void prep_vt(const float* __restrict__ v, __bf16* __restrict__ vt) {
  __shared__ __align__(16) __bf16 lT[DD * VLD];
  const int tid = threadIdx.x;
  const int b = blockIdx.y;
  const int s0 = blockIdx.x * 64;

  const int key = tid >> 2;
  const int dc = (tid & 3) * 32;
  const float* src = v + ((size_t)b * SS + s0 + key) * DD + dc;
#pragma unroll
  for (int i = 0; i < 8; ++i) {
    float4 f = ((const float4*)src)[i];
    lT[(dc + i * 4 + 0) * VLD + key] = (__bf16)f.x;
    lT[(dc + i * 4 + 1) * VLD + key] = (__bf16)f.y;
    lT[(dc + i * 4 + 2) * VLD + key] = (__bf16)f.z;
    lT[(dc + i * 4 + 3) * VLD + key] = (__bf16)f.w;
  }
  __syncthreads();
#pragma unroll
  for (int j = 0; j < 4; ++j) {
    int c = tid + j * 256;          // 1024 chunks: 128 d x 8 s-chunks
    int d = c >> 3, sc2 = c & 7;
    bf16x8 w = *(const bf16x8*)(lT + d * VLD + sc2 * 8);
    *(bf16x8*)(vt + ((size_t)b * DD + d) * SS + s0 + sc2 * 8) = w;
  }
}

// ============================================================
// Fused attention: zero-barrier, staging-free, swapped-operand QK.
// Each wave owns 16 q-rows; K/V frags come straight from L2.
// mfma(K_frag, Q_frag): C col(l16)=q, C row(quad*4+r)=key -> each lane
// holds a 16-key slice of ONE q-row => softmax reduce = 2 shuffles,
// attn written directly from f32 regs, P->LDS is wave-private (4x b64).
// ============================================================
__global__ __launch_bounds__(256, 2)
void attn_fused(const __bf16* __restrict__ qs, const __bf16* __restrict__ kb,
                const __bf16* __restrict__ vt, float* __restrict__ ctx,
                float* __restrict__ attn) {
  // wave-private P tiles: 4 waves x 16 q-rows x 64 keys (bf16), 9216 B total
  __shared__ __align__(16) __bf16 lP[4 * 16 * PLD];

  const int tid  = threadIdx.x;
  const int wave = tid >> 6;
  const int lane = tid & 63;
  const int quad = lane >> 4;
  const int l16  = lane & 15;

  // XCD-aware mapping: dispatch round-robins XCDs (xcd = id % 8); give each
  // XCD 2 batches so its K+V working set (2 MiB bf16) stays L2-resident.
  const int d   = blockIdx.x;            // 0..511
  const int xcd = d & 7;
  const int j   = d >> 3;                // 0..63
  const int b   = 2 * xcd + (j & 1);     // batch
  const int q0  = (j >> 1) * BQ;         // q-block origin

  const int qrow = q0 + wave * 16 + l16; // this lane's q-row (n-dim)

  const __bf16* kbase = kb + (size_t)b * SS * DD;
  const __bf16* vbase = vt + (size_t)b * DD * SS;

  // Q fragment (B-operand): n = l16 = q-row, k = ks*32 + quad*8 + j
  bf16x8 aq[4];
  {
    const __bf16* qp = qs + ((size_t)b * SS + qrow) * DD;
#pragma unroll
    for (int ks = 0; ks < 4; ++ks)
      aq[ks] = *(const bf16x8*)(qp + ks * 32 + quad * 8);
  }

  // ================= Phase 1: softmax stats (online max/sum) =============
  float m = -1e30f, l = 0.0f;
  for (int kt = 0; kt < SS / BK; ++kt) {
    const __bf16* kt0 = kbase + (size_t)(kt * BK) * DD;
    f32x4 sacc[4];
#pragma unroll
    for (int nb = 0; nb < 4; ++nb) sacc[nb] = (f32x4){0.f, 0.f, 0.f, 0.f};
#pragma unroll
    for (int nb = 0; nb < 4; ++nb)
#pragma unroll
      for (int ks = 0; ks < 4; ++ks) {
        bf16x8 ak = *(const bf16x8*)(kt0 + (size_t)(nb * 16 + l16) * DD + ks * 32 + quad * 8);
        sacc[nb] = __builtin_amdgcn_mfma_f32_16x16x32_bf16(ak, aq[ks], sacc[nb], 0, 0, 0);
      }
    // lane holds S[q=qrow][key = kt*64 + nb*16 + quad*4 + r], 16 values
    float tm = -1e30f;
#pragma unroll
    for (int nb = 0; nb < 4; ++nb)
#pragma unroll
      for (int r = 0; r < 4; ++r) tm = fmaxf(tm, sacc[nb][r]);
    tm = fmaxf(tm, __shfl_xor(tm, 16));
    tm = fmaxf(tm, __shfl_xor(tm, 32));
    float mnew = fmaxf(m, tm);
    float ps = 0.0f;
#pragma unroll
    for (int nb = 0; nb < 4; ++nb)
#pragma unroll
      for (int r = 0; r < 4; ++r) ps += __expf(sacc[nb][r] - mnew);
    ps += __shfl_xor(ps, 16);
    ps += __shfl_xor(ps, 32);
    l = l * __expf(m - mnew) + ps;
    m = mnew;
  }
  const float mu = m + __logf(l);

  // ================= Phase 2: attn write + PV =============
  f32x4 cacc[8];
#pragma unroll
  for (int nb = 0; nb < 8; ++nb) cacc[nb] = (f32x4){0.f, 0.f, 0.f, 0.f};

  __bf16* myP = lP + wave * 16 * PLD;
  float* arow = attn + ((size_t)b * SS + qrow) * (size_t)SS + quad * 4;

  for (int kt = 0; kt < SS / BK; ++kt) {
    const int kk0 = kt * BK;
    const __bf16* kt0 = kbase + (size_t)kk0 * DD;
    f32x4 sacc[4];
#pragma unroll
    for (int nb = 0; nb < 4; ++nb) sacc[nb] = (f32x4){0.f, 0.f, 0.f, 0.f};
#pragma unroll
    for (int nb = 0; nb < 4; ++nb)
#pragma unroll
      for (int ks = 0; ks < 4; ++ks) {
        bf16x8 ak = *(const bf16x8*)(kt0 + (size_t)(nb * 16 + l16) * DD + ks * 32 + quad * 8);
        sacc[nb] = __builtin_amdgcn_mfma_f32_16x16x32_bf16(ak, aq[ks], sacc[nb], 0, 0, 0);
      }

    // p = exp(s - mu): write attn directly (f32, nontemporal), P -> LDS bf16
#pragma unroll
    for (int nb = 0; nb < 4; ++nb) {
      f32x4 o;
      o[0] = __expf(sacc[nb][0] - mu);
      o[1] = __expf(sacc[nb][1] - mu);
      o[2] = __expf(sacc[nb][2] - mu);
      o[3] = __expf(sacc[nb][3] - mu);
      __builtin_nontemporal_store(o, (f32x4*)(arow + kk0 + nb * 16));
      bf16x4 pk;
      pk[0] = (__bf16)o[0]; pk[1] = (__bf16)o[1];
      pk[2] = (__bf16)o[2]; pk[3] = (__bf16)o[3];
      *(bf16x4*)(myP + l16 * PLD + nb * 16 + quad * 4) = pk;
    }
    // PV: wave-private lP -> A-frag (compiler inserts lgkmcnt; no barrier
    // needed, producer and consumer are the same wave)
#pragma unroll
    for (int kk = 0; kk < 2; ++kk) {
      bf16x8 ap = *(const bf16x8*)(myP + l16 * PLD + kk * 32 + quad * 8);
#pragma unroll
      for (int nb = 0; nb < 8; ++nb) {
        bf16x8 bv = *(const bf16x8*)(vbase + (size_t)(nb * 16 + l16) * SS + kk0 + kk * 32 + quad * 8);
        cacc[nb] = __builtin_amdgcn_mfma_f32_16x16x32_bf16(ap, bv, cacc[nb], 0, 0, 0);
      }
    }
  }

  // ---- store context (row = q0 + wave*16 + quad*4 + r, col = nb*16+l16) ----
#pragma unroll
  for (int nb = 0; nb < 8; ++nb)
#pragma unroll
    for (int r = 0; r < 4; ++r)
      __builtin_nontemporal_store(
          cacc[nb][r],
          ctx + ((size_t)b * SS + q0 + wave * 16 + quad * 4 + r) * DD + nb * 16 + l16);
}

extern "C" void kernel_launch(void* const* d_in, const int* in_sizes, int n_in,
                              void* d_out, int out_size, void* d_ws, size_t ws_size,
                              hipStream_t stream) {
  const float* q = (const float*)d_in[0];
  const float* k = (const float*)d_in[1];
  const float* v = (const float*)d_in[2];
  float* ctx  = (float*)d_out;
  float* attn = ctx + (size_t)BB * SS * DD;

  __bf16* qs = (__bf16*)d_ws;
  __bf16* kb = qs + (size_t)NELEM;
  __bf16* vt = kb + (size_t)NELEM;

  prep_qk<<<2 * (NELEM / 8) / 256, 256, 0, stream>>>(q, k, qs, kb);
  prep_vt<<<dim3(SS / 64, BB), 256, 0, stream>>>(v, vt);
  attn_fused<<<dim3(512), 256, 0, stream>>>(qs, kb, vt, ctx, attn);
}